// Round 1
// baseline (695.480 us; speedup 1.0000x reference)
//
#include <hip/hip_runtime.h>
#include <stdint.h>

#define B_ROWS 4096
#define N_FEAT 32768
#define K_DIM  1024
#define BM 128
#define BN 128
#define BK 64
#define NT (N_FEAT / BN)   // 256 n-tiles

typedef __attribute__((ext_vector_type(8))) short bf16x8;
typedef __attribute__((ext_vector_type(4))) float f32x4;
typedef __attribute__((address_space(1))) unsigned char ga_u8;
typedef __attribute__((address_space(3))) unsigned char lds_u8;

__device__ inline unsigned short f2bf(float f) {
  union { float f; unsigned u; } v; v.f = f;
  unsigned r = v.u + 0x7FFF + ((v.u >> 16) & 1);
  return (unsigned short)(r >> 16);
}
__device__ inline float bf2f(unsigned short u) {
  union { unsigned u; float f; } v; v.u = ((unsigned)u) << 16;
  return v.f;
}

// ---------------- K0: L2-normalize rows of inputs, cast to bf16 ----------------
__global__ void k_norm(const float* __restrict__ in, unsigned short* __restrict__ xbf) {
  int row = blockIdx.x;
  int t = threadIdx.x;                       // 256 threads, 4 elems each
  float4 v = reinterpret_cast<const float4*>(in + (size_t)row * K_DIM)[t];
  float ssq = v.x * v.x + v.y * v.y + v.z * v.z + v.w * v.w;
  #pragma unroll
  for (int d = 1; d < 64; d <<= 1) ssq += __shfl_xor(ssq, d);
  __shared__ float sm[4];
  if ((t & 63) == 0) sm[t >> 6] = ssq;
  __syncthreads();
  float nrm = sqrtf(sm[0] + sm[1] + sm[2] + sm[3]);
  float inv = 1.0f / fmaxf(nrm, 1e-12f);
  ushort4 o;
  o.x = f2bf(v.x * inv); o.y = f2bf(v.y * inv);
  o.z = f2bf(v.z * inv); o.w = f2bf(v.w * inv);
  reinterpret_cast<ushort4*>(xbf + (size_t)row * K_DIM)[t] = o;
}

// ---------------- K1: cast features f32 -> bf16 ----------------
__global__ void k_conv(const float* __restrict__ f, unsigned short* __restrict__ fbf, long n4) {
  long i = blockIdx.x * (long)blockDim.x + threadIdx.x;
  long stride = (long)gridDim.x * blockDim.x;
  for (; i < n4; i += stride) {
    float4 v = reinterpret_cast<const float4*>(f)[i];
    ushort4 o;
    o.x = f2bf(v.x); o.y = f2bf(v.y); o.z = f2bf(v.z); o.w = f2bf(v.w);
    reinterpret_cast<ushort4*>(fbf)[i] = o;
  }
}

// ---------------- K2: target-column logit, one wave per row ----------------
__global__ void k_tgt(const unsigned short* __restrict__ xbf,
                      const unsigned short* __restrict__ fbf,
                      const int* __restrict__ tgt, float* __restrict__ out) {
  int row = blockIdx.x * 4 + (threadIdx.x >> 6);
  int lane = threadIdx.x & 63;
  int t = tgt[row];
  const uint4* xa = reinterpret_cast<const uint4*>(xbf + (size_t)row * K_DIM + lane * 16);
  const uint4* fa = reinterpret_cast<const uint4*>(fbf + (size_t)t * K_DIM + lane * 16);
  float s = 0.f;
  #pragma unroll
  for (int j = 0; j < 2; ++j) {
    uint4 av = xa[j], fv = fa[j];
    const unsigned* ap = &av.x;
    const unsigned* fp = &fv.x;
    #pragma unroll
    for (int q = 0; q < 4; ++q) {
      s += bf2f((unsigned short)(ap[q] & 0xffff)) * bf2f((unsigned short)(fp[q] & 0xffff));
      s += bf2f((unsigned short)(ap[q] >> 16)) * bf2f((unsigned short)(fp[q] >> 16));
    }
  }
  #pragma unroll
  for (int d = 1; d < 64; d <<= 1) s += __shfl_xor(s, d);
  if (lane == 0) out[row] = s * 20.0f;
}

// ---------------- K3: fused GEMM + per-tile online logsumexp partials ----------------
__launch_bounds__(256)
__global__ void k_gemm(const unsigned short* __restrict__ xbf,
                       const unsigned short* __restrict__ fbf,
                       float* __restrict__ m_part, float* __restrict__ l_part) {
  __shared__ __align__(16) unsigned short As[BM * BK];
  __shared__ __align__(16) unsigned short Bs[BN * BK];
  __shared__ float sm_m[2][BM];
  __shared__ float sm_l[2][BM];

  int nt = blockIdx.x;
  int mt = blockIdx.y;
  int mBase = mt * BM, nBase = nt * BN;

  int tid = threadIdx.x;
  int lane = tid & 63;
  int wid = tid >> 6;
  int wr = wid >> 1, wc = wid & 1;

  f32x4 acc[4][4];
  #pragma unroll
  for (int i = 0; i < 4; ++i)
    #pragma unroll
    for (int j = 0; j < 4; ++j)
      acc[i][j] = (f32x4){0.f, 0.f, 0.f, 0.f};

  int srow = lane >> 3;          // 8 loads of 16B per 64-elem row
  int scol = (lane & 7) * 8;

  for (int kt = 0; kt < K_DIM; kt += BK) {
    __syncthreads();
    #pragma unroll
    for (int i = 0; i < 4; ++i) {
      int chunk = i * 4 + wid;                 // 16 chunks of 512 elems
      int row = chunk * 8 + srow;
      const unsigned short* ga = xbf + (size_t)(mBase + row) * K_DIM + kt + scol;
      __builtin_amdgcn_global_load_lds((const ga_u8*)ga, (lds_u8*)(As + chunk * 512), 16, 0, 0);
      const unsigned short* gb = fbf + (size_t)(nBase + row) * K_DIM + kt + scol;
      __builtin_amdgcn_global_load_lds((const ga_u8*)gb, (lds_u8*)(Bs + chunk * 512), 16, 0, 0);
    }
    __syncthreads();
    #pragma unroll
    for (int ks = 0; ks < 2; ++ks) {
      bf16x8 a[4], b[4];
      #pragma unroll
      for (int fm = 0; fm < 4; ++fm) {
        int r = wr * 64 + fm * 16 + (lane & 15);
        a[fm] = *reinterpret_cast<const bf16x8*>(&As[r * BK + ks * 32 + (lane >> 4) * 8]);
      }
      #pragma unroll
      for (int fn = 0; fn < 4; ++fn) {
        int r = wc * 64 + fn * 16 + (lane & 15);
        b[fn] = *reinterpret_cast<const bf16x8*>(&Bs[r * BK + ks * 32 + (lane >> 4) * 8]);
      }
      #pragma unroll
      for (int fm = 0; fm < 4; ++fm)
        #pragma unroll
        for (int fn = 0; fn < 4; ++fn)
          acc[fm][fn] = __builtin_amdgcn_mfma_f32_16x16x32_bf16(a[fm], b[fn], acc[fm][fn], 0, 0, 0);
    }
  }

  // scale by 1/temp = 20
  #pragma unroll
  for (int fm = 0; fm < 4; ++fm)
    #pragma unroll
    for (int fn = 0; fn < 4; ++fn)
      acc[fm][fn] = acc[fm][fn] * 20.0f;

  // per-row (max, sum-exp) over this wave's 64 columns.
  // C layout: acc[fm][fn][reg] = C[wr*64 + fm*16 + (lane>>4)*4 + reg][wc*64 + fn*16 + (lane&15)]
  int g = lane >> 4;
  #pragma unroll
  for (int fm = 0; fm < 4; ++fm) {
    #pragma unroll
    for (int reg = 0; reg < 4; ++reg) {
      float mx = -1e30f;
      #pragma unroll
      for (int fn = 0; fn < 4; ++fn) mx = fmaxf(mx, acc[fm][fn][reg]);
      mx = fmaxf(mx, __shfl_xor(mx, 1));
      mx = fmaxf(mx, __shfl_xor(mx, 2));
      mx = fmaxf(mx, __shfl_xor(mx, 4));
      mx = fmaxf(mx, __shfl_xor(mx, 8));
      float sum = 0.f;
      #pragma unroll
      for (int fn = 0; fn < 4; ++fn) sum += __expf(acc[fm][fn][reg] - mx);
      sum += __shfl_xor(sum, 1);
      sum += __shfl_xor(sum, 2);
      sum += __shfl_xor(sum, 4);
      sum += __shfl_xor(sum, 8);
      if ((lane & 15) == 0) {
        int r = wr * 64 + fm * 16 + g * 4 + reg;
        sm_m[wc][r] = mx;
        sm_l[wc][r] = sum;
      }
    }
  }
  __syncthreads();
  if (tid < BM) {
    float m0 = sm_m[0][tid], m1 = sm_m[1][tid];
    float l0 = sm_l[0][tid], l1 = sm_l[1][tid];
    float m = fmaxf(m0, m1);
    float l = l0 * __expf(m0 - m) + l1 * __expf(m1 - m);
    size_t idx = (size_t)(mBase + tid) * NT + nt;
    m_part[idx] = m;
    l_part[idx] = l;
  }
}

// ---------------- K4: combine 256 partials per row -> nll ----------------
__global__ void k_comb(const float* __restrict__ m_part, const float* __restrict__ l_part,
                       const float* __restrict__ tgt_logit, float* __restrict__ nll) {
  int row = blockIdx.x;
  int t = threadIdx.x;   // 256
  float m = m_part[(size_t)row * NT + t];
  float l = l_part[(size_t)row * NT + t];
  #pragma unroll
  for (int d = 1; d < 64; d <<= 1) {
    float mo = __shfl_xor(m, d);
    float lo = __shfl_xor(l, d);
    float mn = fmaxf(m, mo);
    l = l * __expf(m - mn) + lo * __expf(mo - mn);
    m = mn;
  }
  __shared__ float smm[4], sml[4];
  if ((t & 63) == 0) { smm[t >> 6] = m; sml[t >> 6] = l; }
  __syncthreads();
  if (t == 0) {
    float M = smm[0], L = sml[0];
    #pragma unroll
    for (int w = 1; w < 4; ++w) {
      float mn = fmaxf(M, smm[w]);
      L = L * __expf(M - mn) + sml[w] * __expf(smm[w] - mn);
      M = mn;
    }
    nll[row] = M + __logf(L) - tgt_logit[row];
  }
}

// ---------------- K5: mean over rows -> out[0] ----------------
__global__ void k_mean(const float* __restrict__ nll, float* __restrict__ out) {
  int t = threadIdx.x;   // 256
  float s = 0.f;
  for (int i = t; i < B_ROWS; i += 256) s += nll[i];
  #pragma unroll
  for (int d = 1; d < 64; d <<= 1) s += __shfl_xor(s, d);
  __shared__ float sm[4];
  if ((t & 63) == 0) sm[t >> 6] = s;
  __syncthreads();
  if (t == 0) out[0] = (sm[0] + sm[1] + sm[2] + sm[3]) * (1.0f / B_ROWS);
}

extern "C" void kernel_launch(void* const* d_in, const int* in_sizes, int n_in,
                              void* d_out, int out_size, void* d_ws, size_t ws_size,
                              hipStream_t stream) {
  const float* inputs = (const float*)d_in[0];
  // d_in[1] = targets (unused by the loss)
  const int* ctgt = (const int*)d_in[2];
  const float* feats = (const float*)d_in[3];
  float* out = (float*)d_out;

  char* ws = (char*)d_ws;
  unsigned short* xbf = (unsigned short*)ws;                          // 8 MB
  unsigned short* fbf = (unsigned short*)(ws + (8ull << 20));         // 64 MB
  float* m_part = (float*)(ws + (72ull << 20));                       // 4 MB
  float* l_part = (float*)(ws + (76ull << 20));                       // 4 MB
  float* tgt_logit = (float*)(ws + (80ull << 20));                    // 16 KB
  float* nll = (float*)(ws + (80ull << 20) + (64ull << 10));          // 16 KB

  k_norm<<<B_ROWS, 256, 0, stream>>>(inputs, xbf);
  k_conv<<<2048, 256, 0, stream>>>(feats, fbf, (long)N_FEAT * K_DIM / 4);
  k_tgt<<<B_ROWS / 4, 256, 0, stream>>>(xbf, fbf, ctgt, tgt_logit);
  dim3 g3(NT, B_ROWS / BM);
  k_gemm<<<g3, 256, 0, stream>>>(xbf, fbf, m_part, l_part);
  k_comb<<<B_ROWS, 256, 0, stream>>>(m_part, l_part, tgt_logit, nll);
  k_mean<<<1, 256, 0, stream>>>(nll, out);
}

// Round 2
// 521.798 us; speedup vs baseline: 1.3329x; 1.3329x over previous
//
#include <hip/hip_runtime.h>
#include <stdint.h>

#define B_ROWS 4096
#define N_FEAT 32768
#define K_DIM  1024
#define BM 256
#define BN 256
#define NT2 (N_FEAT / BN)   // 128 n-tiles
#define NKT (K_DIM / 64)    // 16 K-tiles

typedef __attribute__((ext_vector_type(8))) short bf16x8;
typedef __attribute__((ext_vector_type(4))) float f32x4;
typedef __attribute__((address_space(1))) unsigned char ga_u8;
typedef __attribute__((address_space(3))) unsigned char lds_u8;

__device__ inline unsigned short f2bf(float f) {
  union { float f; unsigned u; } v; v.f = f;
  unsigned r = v.u + 0x7FFF + ((v.u >> 16) & 1);
  return (unsigned short)(r >> 16);
}
__device__ inline float bf2f(unsigned short u) {
  union { unsigned u; float f; } v; v.u = ((unsigned)u) << 16;
  return v.f;
}

// ---------------- K0: L2-normalize rows of inputs, cast to bf16 ----------------
__global__ void k_norm(const float* __restrict__ in, unsigned short* __restrict__ xbf) {
  int row = blockIdx.x;
  int t = threadIdx.x;                       // 256 threads, 4 elems each
  float4 v = reinterpret_cast<const float4*>(in + (size_t)row * K_DIM)[t];
  float ssq = v.x * v.x + v.y * v.y + v.z * v.z + v.w * v.w;
  #pragma unroll
  for (int d = 1; d < 64; d <<= 1) ssq += __shfl_xor(ssq, d);
  __shared__ float sm[4];
  if ((t & 63) == 0) sm[t >> 6] = ssq;
  __syncthreads();
  float nrm = sqrtf(sm[0] + sm[1] + sm[2] + sm[3]);
  float inv = 1.0f / fmaxf(nrm, 1e-12f);
  ushort4 o;
  o.x = f2bf(v.x * inv); o.y = f2bf(v.y * inv);
  o.z = f2bf(v.z * inv); o.w = f2bf(v.w * inv);
  reinterpret_cast<ushort4*>(xbf + (size_t)row * K_DIM)[t] = o;
}

// ---------------- K1: cast features f32 -> bf16 ----------------
__global__ void k_conv(const float* __restrict__ f, unsigned short* __restrict__ fbf, long n4) {
  long i = blockIdx.x * (long)blockDim.x + threadIdx.x;
  long stride = (long)gridDim.x * blockDim.x;
  for (; i < n4; i += stride) {
    float4 v = reinterpret_cast<const float4*>(f)[i];
    ushort4 o;
    o.x = f2bf(v.x); o.y = f2bf(v.y); o.z = f2bf(v.z); o.w = f2bf(v.w);
    reinterpret_cast<ushort4*>(fbf)[i] = o;
  }
}

// ---------------- K2: target-column logit, one wave per row ----------------
__global__ void k_tgt(const unsigned short* __restrict__ xbf,
                      const unsigned short* __restrict__ fbf,
                      const int* __restrict__ tgt, float* __restrict__ out) {
  int row = blockIdx.x * 4 + (threadIdx.x >> 6);
  int lane = threadIdx.x & 63;
  int t = tgt[row];
  const uint4* xa = reinterpret_cast<const uint4*>(xbf + (size_t)row * K_DIM + lane * 16);
  const uint4* fa = reinterpret_cast<const uint4*>(fbf + (size_t)t * K_DIM + lane * 16);
  float s = 0.f;
  #pragma unroll
  for (int j = 0; j < 2; ++j) {
    uint4 av = xa[j], fv = fa[j];
    const unsigned* ap = &av.x;
    const unsigned* fp = &fv.x;
    #pragma unroll
    for (int q = 0; q < 4; ++q) {
      s += bf2f((unsigned short)(ap[q] & 0xffff)) * bf2f((unsigned short)(fp[q] & 0xffff));
      s += bf2f((unsigned short)(ap[q] >> 16)) * bf2f((unsigned short)(fp[q] >> 16));
    }
  }
  #pragma unroll
  for (int d = 1; d < 64; d <<= 1) s += __shfl_xor(s, d);
  if (lane == 0) out[row] = s * 20.0f;
}

// ---------------- K3: 256x256 8-wave 4-phase deep-pipelined GEMM + fused logsumexp ----
// LDS: buf b in [b*65536, +65536): Ak0 @0, Ak1 @16384, Bk0 @32768, Bk1 @49152.
// Region layout: [256 rows][32 k] ushort, row stride 64B.
// Read swizzle: byte-in-row = (g*16) ^ (((row>>1)&3)<<4); staged via pre-swizzled
// global source (LDS dest linear, per global_load_lds constraint).

#define XSTR(s) STR(s)
#define STR(s) #s
#define WAITV(N)  asm volatile("s_waitcnt vmcnt(" XSTR(N) ")" ::: "memory")
#define LGKM0     do { asm volatile("s_waitcnt lgkmcnt(0)" ::: "memory"); __builtin_amdgcn_sched_barrier(0); } while(0)
#define BAR       __builtin_amdgcn_s_barrier()
#define SCHED0    __builtin_amdgcn_sched_barrier(0)
#define PRIO1     __builtin_amdgcn_s_setprio(1)
#define PRIO0     __builtin_amdgcn_s_setprio(0)

__launch_bounds__(512, 2)
__global__ void k_gemm8(const unsigned short* __restrict__ xbf,
                        const unsigned short* __restrict__ fbf,
                        float* __restrict__ m_part, float* __restrict__ l_part) {
  __shared__ __align__(16) char lds_all[131072];
  char* ldsc = lds_all;

  int tid = threadIdx.x;
  int lane = tid & 63;
  int wid = tid >> 6;          // 0..7
  int wr = wid >> 2;           // 0..1
  int wc = wid & 3;            // 0..3
  int r15 = lane & 15;
  int g = lane >> 4;

  // XCD-aware swizzle (2048 blocks, 8 XCDs, 2048%8==0 -> simple bijection)
  int bid = blockIdx.x;
  int swz = (bid & 7) * 256 + (bid >> 3);
  int mt = swz >> 7;           // 0..15
  int nt = swz & 127;          // 0..127
  int mBase = mt * BM, nBase = nt * BN;

  // fragment-read LDS offsets (byte), incl. swizzle
  int lswz = ((g ^ ((r15 >> 1) & 3)) << 4);
  int aRow = (wr * 128 + r15) * 64 + lswz;           // + KH*16384 + Q*4096 + fm*1024
  int bRow = (wc * 64 + r15) * 64 + lswz + 32768;    // + KH*16384 + fn*1024

  // staging: per-thread global source (pre-swizzled), wave-uniform LDS dest
  int stRow = wid * 32 + (lane >> 2);                // 0..255 across waves (j adds 16)
  int src_cb = (((lane & 3) ^ ((lane >> 3) & 3)) << 4);
  const char* srcA = (const char*)xbf + (size_t)(mBase + stRow) * (K_DIM * 2) + src_cb;
  const char* srcB = (const char*)fbf + (size_t)(nBase + stRow) * (K_DIM * 2) + src_cb;

#define STAGE(BSEL_, MAT, KH, T) do { \
    const char* gsrc = ((MAT) ? srcB : srcA) + (T) * 128 + (KH) * 64; \
    char* ldst = ldsc + (BSEL_) * 65536 + (MAT) * 32768 + (KH) * 16384 + wid * 2048; \
    __builtin_amdgcn_global_load_lds((const ga_u8*)gsrc, (lds_u8*)ldst, 16, 0, 0); \
    __builtin_amdgcn_global_load_lds((const ga_u8*)(gsrc + 32768), (lds_u8*)(ldst + 1024), 16, 0, 0); \
  } while(0)

#define LDA(Q, KH, BUFC) do { \
    _Pragma("unroll") \
    for (int fm = 0; fm < 4; ++fm) \
      a[fm] = *reinterpret_cast<const bf16x8*>((BUFC) + (KH) * 16384 + aRow + (Q) * 4096 + fm * 1024); \
  } while(0)

#define LDB(KH, BUFC) do { \
    _Pragma("unroll") \
    for (int fn = 0; fn < 4; ++fn) \
      b[fn] = *reinterpret_cast<const bf16x8*>((BUFC) + (KH) * 16384 + bRow + fn * 1024); \
  } while(0)

#define MM(Q) do { \
    _Pragma("unroll") \
    for (int fm = 0; fm < 4; ++fm) \
      _Pragma("unroll") \
      for (int fn = 0; fn < 4; ++fn) \
        acc[(Q) * 4 + fm][fn] = __builtin_amdgcn_mfma_f32_16x16x32_bf16(a[fm], b[fn], acc[(Q) * 4 + fm][fn], 0, 0, 0); \
  } while(0)

#define TILE(T, ISS1, ISS2, VMA, VMB) do { \
    int bs = (T) & 1; \
    char* bufc = ldsc + bs * 65536; \
    /* ph1: (q0, k0) */ \
    LDA(0, 0, bufc); LDB(0, bufc); \
    if (ISS1) { STAGE(((T) + 1) & 1, 0, 1, (T) + 1); } \
    BAR; LGKM0; PRIO1; MM(0); PRIO0; BAR; SCHED0; \
    /* ph2: (q1, k0) */ \
    LDA(1, 0, bufc); \
    if (ISS1) { STAGE(((T) + 1) & 1, 1, 1, (T) + 1); } \
    WAITV(VMA); \
    BAR; LGKM0; PRIO1; MM(1); PRIO0; BAR; SCHED0; \
    /* ph3: (q0, k1) */ \
    LDA(0, 1, bufc); LDB(1, bufc); \
    if (ISS2) { STAGE(bs, 0, 0, (T) + 2); } \
    BAR; LGKM0; PRIO1; MM(0); PRIO0; BAR; SCHED0; \
    /* ph4: (q1, k1) */ \
    LDA(1, 1, bufc); \
    if (ISS2) { STAGE(bs, 1, 0, (T) + 2); } \
    WAITV(VMB); \
    BAR; LGKM0; PRIO1; MM(1); PRIO0; BAR; SCHED0; \
  } while(0)

  f32x4 acc[8][4];
  #pragma unroll
  for (int i = 0; i < 8; ++i)
    #pragma unroll
    for (int j = 0; j < 4; ++j)
      acc[i][j] = (f32x4){0.f, 0.f, 0.f, 0.f};
  bf16x8 a[4], b[4];

  // Prologue: k0(0), k1(0), k0(1)  (age order matters for the counted waits)
  STAGE(0, 0, 0, 0); STAGE(0, 1, 0, 0);
  STAGE(0, 0, 1, 0); STAGE(0, 1, 1, 0);
  STAGE(1, 0, 0, 1); STAGE(1, 1, 0, 1);
  WAITV(8);
  BAR; SCHED0;

  for (int t = 0; t < NKT - 2; ++t) {       // t = 0..13
    TILE(t, 1, 1, 8, 8);
  }
  TILE(14, 1, 0, 8, 4);
  TILE(15, 0, 0, 0, 0);

  // ---------------- fused epilogue: per-row max + sumexp over this block's 256 cols
  asm volatile("s_waitcnt vmcnt(0) lgkmcnt(0)" ::: "memory");
  __syncthreads();
  float* sm_m = (float*)lds_all;            // [4][256]
  float* sm_l = (float*)(lds_all + 4096);

  #pragma unroll
  for (int mf = 0; mf < 8; ++mf)
    #pragma unroll
    for (int fn = 0; fn < 4; ++fn)
      acc[mf][fn] = acc[mf][fn] * 20.0f;    // 1/temp

  #pragma unroll
  for (int mf = 0; mf < 8; ++mf) {
    #pragma unroll
    for (int reg = 0; reg < 4; ++reg) {
      float mx = -1e30f;
      #pragma unroll
      for (int fn = 0; fn < 4; ++fn) mx = fmaxf(mx, acc[mf][fn][reg]);
      mx = fmaxf(mx, __shfl_xor(mx, 1));
      mx = fmaxf(mx, __shfl_xor(mx, 2));
      mx = fmaxf(mx, __shfl_xor(mx, 4));
      mx = fmaxf(mx, __shfl_xor(mx, 8));
      float sum = 0.f;
      #pragma unroll
      for (int fn = 0; fn < 4; ++fn) sum += __expf(acc[mf][fn][reg] - mx);
      sum += __shfl_xor(sum, 1);
      sum += __shfl_xor(sum, 2);
      sum += __shfl_xor(sum, 4);
      sum += __shfl_xor(sum, 8);
      if ((lane & 15) == 0) {
        int r = wr * 128 + mf * 16 + (lane >> 4) * 4 + reg;
        sm_m[wc * 256 + r] = mx;
        sm_l[wc * 256 + r] = sum;
      }
    }
  }
  __syncthreads();
  if (tid < 256) {
    float M = sm_m[tid], L = sm_l[tid];
    #pragma unroll
    for (int w = 1; w < 4; ++w) {
      float mo = sm_m[w * 256 + tid], lo = sm_l[w * 256 + tid];
      float mn = fmaxf(M, mo);
      L = L * __expf(M - mn) + lo * __expf(mo - mn);
      M = mn;
    }
    size_t idx = (size_t)(mBase + tid) * NT2 + nt;
    m_part[idx] = M;
    l_part[idx] = L;
  }
}

// ---------------- K4: combine 128 partials per row -> nll ----------------
__global__ void k_comb(const float* __restrict__ m_part, const float* __restrict__ l_part,
                       const float* __restrict__ tgt_logit, float* __restrict__ nll) {
  int row = blockIdx.x;
  int lane = threadIdx.x;   // 64
  size_t base = (size_t)row * NT2;
  float m = m_part[base + lane];
  float l = l_part[base + lane];
  float m2 = m_part[base + 64 + lane];
  float l2 = l_part[base + 64 + lane];
  float mn = fmaxf(m, m2);
  l = l * __expf(m - mn) + l2 * __expf(m2 - mn);
  m = mn;
  #pragma unroll
  for (int d = 1; d < 64; d <<= 1) {
    float mo = __shfl_xor(m, d);
    float lo = __shfl_xor(l, d);
    float mx = fmaxf(m, mo);
    l = l * __expf(m - mx) + lo * __expf(mo - mx);
    m = mx;
  }
  if (lane == 0) nll[row] = m + __logf(l) - tgt_logit[row];
}

// ---------------- K5: mean over rows -> out[0] ----------------
__global__ void k_mean(const float* __restrict__ nll, float* __restrict__ out) {
  int t = threadIdx.x;   // 256
  float s = 0.f;
  for (int i = t; i < B_ROWS; i += 256) s += nll[i];
  #pragma unroll
  for (int d = 1; d < 64; d <<= 1) s += __shfl_xor(s, d);
  __shared__ float sm[4];
  if ((t & 63) == 0) sm[t >> 6] = s;
  __syncthreads();
  if (t == 0) out[0] = (sm[0] + sm[1] + sm[2] + sm[3]) * (1.0f / B_ROWS);
}

extern "C" void kernel_launch(void* const* d_in, const int* in_sizes, int n_in,
                              void* d_out, int out_size, void* d_ws, size_t ws_size,
                              hipStream_t stream) {
  const float* inputs = (const float*)d_in[0];
  // d_in[1] = targets (unused by the loss)
  const int* ctgt = (const int*)d_in[2];
  const float* feats = (const float*)d_in[3];
  float* out = (float*)d_out;

  char* ws = (char*)d_ws;
  unsigned short* xbf = (unsigned short*)ws;                          // 8 MB
  unsigned short* fbf = (unsigned short*)(ws + (8ull << 20));         // 64 MB
  float* m_part = (float*)(ws + (72ull << 20));                       // 2 MB
  float* l_part = (float*)(ws + (74ull << 20));                       // 2 MB
  float* tgt_logit = (float*)(ws + (76ull << 20));                    // 16 KB
  float* nll = (float*)(ws + (76ull << 20) + (64ull << 10));          // 16 KB

  k_norm<<<B_ROWS, 256, 0, stream>>>(inputs, xbf);
  k_conv<<<2048, 256, 0, stream>>>(feats, fbf, (long)N_FEAT * K_DIM / 4);
  k_tgt<<<B_ROWS / 4, 256, 0, stream>>>(xbf, fbf, ctgt, tgt_logit);
  k_gemm8<<<(B_ROWS / BM) * (N_FEAT / BN), 512, 0, stream>>>(xbf, fbf, m_part, l_part);
  k_comb<<<B_ROWS, 64, 0, stream>>>(m_part, l_part, tgt_logit, nll);
  k_mean<<<1, 256, 0, stream>>>(nll, out);
}